// Round 2
// baseline (215.741 us; speedup 1.0000x reference)
//
#include <hip/hip_runtime.h>

// NRC fused encode + 7-layer W=64 MLP, f16 MFMA (16x16x32), fp32 accumulate.
// Layout notes (verified fragment maps for gfx950 16x16x32 f16/bf16):
//   A[m=lane&15][k=(lane>>4)*8+j]   (A = weight rows, M = out features)
//   B[k=(lane>>4)*8+j][n=lane&15]   (B = h^T, N = samples)
//   D[row=(lane>>4)*4+r][col=lane&15]
// h stored in LDS in B-fragment-native chunks: chunk fc=(kt*4+q) holds
// features f=fc*8..fc*8+7 for each of 16 samples, 16B per (chunk,row).

typedef _Float16 f16;
typedef f16 f16x2 __attribute__((ext_vector_type(2)));
typedef f16 f16x4 __attribute__((ext_vector_type(4)));
typedef f16 f16x8 __attribute__((ext_vector_type(8)));
typedef float f32x4 __attribute__((ext_vector_type(4)));

#define MFMA16(A, B, C) __builtin_amdgcn_mfma_f32_16x16x32_f16(A, B, C, 0, 0, 0)

static constexpr int TILES = 8;                  // 16-sample tiles per wave
static constexpr int WAVES = 2;                  // waves per block
static constexpr int BLOCK = WAVES * 64;         // 128 threads
static constexpr int SPB   = WAVES * TILES * 16; // 256 samples per block

__device__ __forceinline__ f16x2 pkh(float a, float b) {
    return __builtin_bit_cast(f16x2, __builtin_amdgcn_cvt_pkrtz(a, b));
}

__device__ __forceinline__ f16x8 pack8(const float* f) {
    f16x2 a = pkh(f[0], f[1]);
    f16x2 b = pkh(f[2], f[3]);
    f16x2 c = pkh(f[4], f[5]);
    f16x2 d = pkh(f[6], f[7]);
    f16x8 v;
    v[0] = a[0]; v[1] = a[1]; v[2] = b[0]; v[3] = b[1];
    v[4] = c[0]; v[5] = c[1]; v[6] = d[0]; v[7] = d[1];
    return v;
}

__device__ __forceinline__ f16x8 load_wfrag(const float* __restrict__ Wl, int row, int k0) {
    const f32x4 lo = *(const f32x4*)(Wl + row * 64 + k0);
    const f32x4 hi = *(const f32x4*)(Wl + row * 64 + k0 + 4);
    float t[8] = {lo[0], lo[1], lo[2], lo[3], hi[0], hi[1], hi[2], hi[3]};
    return pack8(t);
}

__global__ __launch_bounds__(BLOCK, 2) void nrc_mlp_kernel(
    const float* __restrict__ P,  const float* __restrict__ WI,
    const float* __restrict__ NV, const float* __restrict__ AL,
    const float* __restrict__ BE, const float* __restrict__ RR,
    const float* __restrict__ W0, const float* __restrict__ W1,
    const float* __restrict__ W2, const float* __restrict__ W3,
    const float* __restrict__ W4, const float* __restrict__ W5,
    const float* __restrict__ W6, float* __restrict__ Out)
{
    // LDS: [0,2048) W6 frags | [2048, 2048+W*T*2048) h tiles | then ab (alpha+beta)
    __shared__ __attribute__((aligned(16)))
        unsigned char smem[2048 + WAVES * TILES * 2048 + WAVES * TILES * 16 * 16];

    const int tid  = threadIdx.x;
    const int lane = tid & 63;
    const int w    = tid >> 6;
    const int q    = lane >> 4;
    const int m    = lane & 15;

    unsigned char* const w6b = smem;
    unsigned char* const hb  = smem + 2048 + w * (TILES * 2048);
    unsigned char* const abb = smem + 2048 + WAVES * TILES * 2048 + w * (TILES * 16 * 16);

    const int wave_base = (int)blockIdx.x * SPB + w * (TILES * 16);

    // ---- stage W6 fragments into LDS (rows padded 3 -> 16 with zeros) ----
    {
        const int kt = tid >> 6;   // 0..1 (128 threads)
        const int l2 = tid & 63;
        const int mm = l2 & 15, qq = l2 >> 4;
        f16x8 v;
#pragma unroll
        for (int j = 0; j < 8; ++j) {
            const int k = kt * 32 + qq * 8 + j;
            const float val = (mm < 3) ? W6[mm * 64 + k] : 0.0f;
            v[j] = (f16)val;
        }
        *(f16x8*)(w6b + (kt * 64 + l2) * 16) = v;
    }
    __syncthreads();

    // ---- encode: 2 chunks x 64 samples (one sample per lane) ----
#pragma unroll
    for (int c = 0; c < 2; ++c) {
        const int sl = c * 64 + lane;        // local sample in wave (0..127)
        const int s  = wave_base + sl;       // global sample

        float pv[3], wv[3], nv[3], av[3], bv[3];
#pragma unroll
        for (int d = 0; d < 3; ++d) {
            pv[d] = P [s * 3 + d];
            wv[d] = WI[s * 3 + d];
            nv[d] = NV[s * 3 + d];
            av[d] = AL[s * 3 + d];
            bv[d] = BE[s * 3 + d];
        }
        const float rv = RR[s];

        float feat[64];
        // frequency embedding: feat[d*12 + k] = sin, feat[d*12 + 6 + k] = cos
#pragma unroll
        for (int d = 0; d < 3; ++d) {
            const float ang0 = 3.14159265358979323846f * pv[d];
#pragma unroll
            for (int k = 0; k < 6; ++k) {
                float sn, cs;
                __sincosf(ang0 * (float)(1 << k), &sn, &cs);
                feat[d * 12 + k]     = sn;
                feat[d * 12 + 6 + k] = cs;
            }
        }
        // sph + one-blob for wi (36..43) and n (44..51)
#pragma unroll
        for (int which = 0; which < 2; ++which) {
            const float* dv = (which == 0) ? wv : nv;
            const int fo = 36 + which * 8;
            const float nr = sqrtf(dv[0]*dv[0] + dv[1]*dv[1] + dv[2]*dv[2]) + 1e-8f;
            const float u  = atan2f(dv[1], dv[0]) * 0.15915494309189535f + 0.5f;
            float zc = dv[2] / nr;
            zc = fminf(fmaxf(zc, -1.0f + 1e-6f), 1.0f - 1e-6f);
            const float vv = acosf(zc) * 0.3183098861837907f;
#pragma unroll
            for (int i = 0; i < 4; ++i) {
                const float cc = (i + 0.5f) * 0.25f;
                const float du = u - cc, dvv = vv - cc;
                feat[fo + i]     = __expf(-8.0f * du * du);
                feat[fo + 4 + i] = __expf(-8.0f * dvv * dvv);
            }
        }
        // r one-blob (52..55)
        {
            const float x = 1.0f - __expf(-rv);
#pragma unroll
            for (int i = 0; i < 4; ++i) {
                const float cc = (i + 0.5f) * 0.25f;
                const float dx = x - cc;
                feat[52 + i] = __expf(-8.0f * dx * dx);
            }
        }
        feat[56] = av[0]; feat[57] = av[1]; feat[58] = av[2];
        feat[59] = bv[0]; feat[60] = bv[1]; feat[61] = bv[2];
        feat[62] = 1.0f;  feat[63] = 1.0f;

        // stash alpha+beta for the epilogue
        f32x4 abv;
        abv[0] = av[0] + bv[0]; abv[1] = av[1] + bv[1];
        abv[2] = av[2] + bv[2]; abv[3] = 0.0f;
        *(f32x4*)(abb + sl * 16) = abv;

        // write features to this sample's tile in B-frag-native layout
        unsigned char* const tb = hb + (c * 4 + q) * 2048;
#pragma unroll
        for (int fc = 0; fc < 8; ++fc) {
            f16x8 v = pack8(&feat[fc * 8]);
            *(f16x8*)(tb + fc * 256 + m * 16) = v;
        }
    }
    // NOTE: no barrier needed — each wave's tiles are wave-private;
    // within-wave ds_write -> ds_read ordering is handled by lgkmcnt.

    // ---- hidden layers 0..5 (weight-stationary, tiles inner) ----
    const float* const Ws[6] = {W0, W1, W2, W3, W4, W5};
#pragma unroll
    for (int layer = 0; layer < 6; ++layer) {
        const float* __restrict__ Wl = Ws[layer];
        f16x8 wf[2][4];
#pragma unroll
        for (int kt = 0; kt < 2; ++kt)
#pragma unroll
            for (int mt = 0; mt < 4; ++mt)
                wf[kt][mt] = load_wfrag(Wl, mt * 16 + m, kt * 32 + q * 8);

        for (int t = 0; t < TILES; ++t) {
            unsigned char* const tb = hb + t * 2048;
            const f16x8 bf0 = *(const f16x8*)(tb +        q * 256 + m * 16);
            const f16x8 bf1 = *(const f16x8*)(tb + 1024 + q * 256 + m * 16);
            f32x4 acc[4];
#pragma unroll
            for (int mt = 0; mt < 4; ++mt) {
                f32x4 z = {0.0f, 0.0f, 0.0f, 0.0f};
                z = MFMA16(wf[0][mt], bf0, z);
                z = MFMA16(wf[1][mt], bf1, z);
                acc[mt] = z;
            }
            // ReLU + f16 pack + write back in B-frag layout:
            // lane holds h_next[f = mt*16 + q*4 + r][s = m], r=0..3 contiguous
#pragma unroll
            for (int mt = 0; mt < 4; ++mt) {
                const float r0 = fmaxf(acc[mt][0], 0.0f);
                const float r1 = fmaxf(acc[mt][1], 0.0f);
                const float r2 = fmaxf(acc[mt][2], 0.0f);
                const float r3 = fmaxf(acc[mt][3], 0.0f);
                const f16x2 lo = pkh(r0, r1);
                const f16x2 hi = pkh(r2, r3);
                f16x4 v;
                v[0] = lo[0]; v[1] = lo[1]; v[2] = hi[0]; v[3] = hi[1];
                *(f16x4*)(tb + (mt * 2 + (q >> 1)) * 256 + m * 16 + (q & 1) * 8) = v;
            }
        }
    }

    // ---- final layer (W6, 3 outputs) + scale by (alpha+beta) ----
    {
        const f16x8 w6f0 = *(const f16x8*)(w6b + lane * 16);
        const f16x8 w6f1 = *(const f16x8*)(w6b + (64 + lane) * 16);
        for (int t = 0; t < TILES; ++t) {
            unsigned char* const tb = hb + t * 2048;
            const f16x8 bf0 = *(const f16x8*)(tb +        q * 256 + m * 16);
            const f16x8 bf1 = *(const f16x8*)(tb + 1024 + q * 256 + m * 16);
            f32x4 z = {0.0f, 0.0f, 0.0f, 0.0f};
            z = MFMA16(w6f0, bf0, z);
            z = MFMA16(w6f1, bf1, z);
            const f32x4 abv = *(const f32x4*)(abb + (t * 16 + m) * 16);
            if (lane < 16) {
                // q==0: rows r=0..2 are the 3 output channels for sample col m
                const int s = wave_base + t * 16 + m;
                float* o = Out + s * 3;
                o[0] = z[0] * abv[0];
                o[1] = z[1] * abv[1];
                o[2] = z[2] * abv[2];
            }
        }
    }
}

extern "C" void kernel_launch(void* const* d_in, const int* in_sizes, int n_in,
                              void* d_out, int out_size, void* d_ws, size_t ws_size,
                              hipStream_t stream) {
    (void)n_in; (void)d_ws; (void)ws_size; (void)out_size;
    const float* P  = (const float*)d_in[0];
    const float* WI = (const float*)d_in[1];
    const float* NV = (const float*)d_in[2];
    const float* AL = (const float*)d_in[3];
    const float* BE = (const float*)d_in[4];
    const float* RR = (const float*)d_in[5];
    const float* W0 = (const float*)d_in[6];
    const float* W1 = (const float*)d_in[7];
    const float* W2 = (const float*)d_in[8];
    const float* W3 = (const float*)d_in[9];
    const float* W4 = (const float*)d_in[10];
    const float* W5 = (const float*)d_in[11];
    const float* W6 = (const float*)d_in[12];
    float* Out = (float*)d_out;

    const int Bn = in_sizes[0] / 3;     // 1,048,576
    const int grid = Bn / SPB;          // 4096 blocks of 128 threads

    hipLaunchKernelGGL(nrc_mlp_kernel, dim3(grid), dim3(BLOCK), 0, stream,
                       P, WI, NV, AL, BE, RR, W0, W1, W2, W3, W4, W5, W6, Out);
}